// Round 1
// baseline (132.405 us; speedup 1.0000x reference)
//
#include <hip/hip_runtime.h>

#define BB 32
#define NN 4096
#define NQ 8
#define DD 64
#define DV 64
#define CHUNKS 16
#define TOK_PER_BLOCK (NN / CHUNKS)      // 256
#define TOK_PER_WAVE (TOK_PER_BLOCK / 4) // 64

// Main pass: each wave owns 64 tokens. Lane = m*8+g: m = query slot (0..7),
// g = dim octet (0..7). Q fragment lives in 8 regs/lane. Scores via per-lane
// FMA + xor(1,2,4) butterfly over g; softmax over m via xor(8,16,32).
// Accumulate U[m][8g+j] in regs, block-reduce in LDS, atomicAdd to ws.
__global__ __launch_bounds__(256) void slot_attn_main(
    const float* __restrict__ keys, const float* __restrict__ values,
    const float* __restrict__ query, float* __restrict__ U, float* __restrict__ S)
{
    const int b    = blockIdx.y;
    const int chnk = blockIdx.x;
    const int tid  = threadIdx.x;
    const int wave = tid >> 6;
    const int lane = tid & 63;
    const int m    = lane >> 3;
    const int g    = lane & 7;

    // Q[b][m][8g..8g+7] -> 8 regs, loaded once
    const float4* qp = (const float4*)(query + ((size_t)b * NQ + m) * DD + 8 * g);
    const float4 q0 = qp[0];
    const float4 q1 = qp[1];

    const float* Kb = keys   + (size_t)b * NN * DD;
    const float* Vb = values + (size_t)b * NN * DV;

    float u[8];
#pragma unroll
    for (int j = 0; j < 8; ++j) u[j] = 0.f;
    float s_acc = 0.f;

    const int tok0 = chnk * TOK_PER_BLOCK + wave * TOK_PER_WAVE;

    for (int t = tok0; t < tok0 + TOK_PER_WAVE; t += 4) {
        float4 k0[4], k1[4], v0[4], v1[4];
#pragma unroll
        for (int uu = 0; uu < 4; ++uu) {
            const float4* kp = (const float4*)(Kb + (size_t)(t + uu) * DD + 8 * g);
            const float4* vp = (const float4*)(Vb + (size_t)(t + uu) * DV + 8 * g);
            k0[uu] = kp[0]; k1[uu] = kp[1];
            v0[uu] = vp[0]; v1[uu] = vp[1];
        }
#pragma unroll
        for (int uu = 0; uu < 4; ++uu) {
            // partial dot over this lane's 8 dims
            float s = k0[uu].x * q0.x + k0[uu].y * q0.y + k0[uu].z * q0.z + k0[uu].w * q0.w
                    + k1[uu].x * q1.x + k1[uu].y * q1.y + k1[uu].z * q1.z + k1[uu].w * q1.w;
            // reduce over g (lane bits 0..2): all lanes of an m-group get score_m
            s += __shfl_xor(s, 1, 64);
            s += __shfl_xor(s, 2, 64);
            s += __shfl_xor(s, 4, 64);
            s *= 0.125f;  // 1/sqrt(64)
            // softmax over m (lane bits 3..5)
            float mx = s;
            mx = fmaxf(mx, __shfl_xor(mx, 8, 64));
            mx = fmaxf(mx, __shfl_xor(mx, 16, 64));
            mx = fmaxf(mx, __shfl_xor(mx, 32, 64));
            float e = __expf(s - mx);
            float sm = e;
            sm += __shfl_xor(sm, 8, 64);
            sm += __shfl_xor(sm, 16, 64);
            sm += __shfl_xor(sm, 32, 64);
            float alpha = e / sm + 1e-8f;
            s_acc += alpha;
            // accumulate alpha * V[n][8g+j] into U[m][8g+j]
            u[0] += alpha * v0[uu].x;
            u[1] += alpha * v0[uu].y;
            u[2] += alpha * v0[uu].z;
            u[3] += alpha * v0[uu].w;
            u[4] += alpha * v1[uu].x;
            u[5] += alpha * v1[uu].y;
            u[6] += alpha * v1[uu].z;
            u[7] += alpha * v1[uu].w;
        }
    }

    // block-level reduction (4 waves) in LDS, then one atomicAdd per output
    __shared__ float lds[4 * 512];
    __shared__ float lds_s[4 * 8];
    float* dst = lds + wave * 512 + m * 64 + 8 * g;
#pragma unroll
    for (int j = 0; j < 8; ++j) dst[j] = u[j];
    if (g == 0) lds_s[wave * 8 + m] = s_acc;
    __syncthreads();

#pragma unroll
    for (int o = 0; o < 2; ++o) {
        int idx = o * 256 + tid;
        float sum = lds[idx] + lds[512 + idx] + lds[1024 + idx] + lds[1536 + idx];
        atomicAdd(U + (size_t)b * (NQ * DV) + idx, sum);
    }
    if (tid < 8) {
        float ssum = lds_s[tid] + lds_s[8 + tid] + lds_s[16 + tid] + lds_s[24 + tid];
        atomicAdd(S + b * NQ + tid, ssum);
    }
}

// out[b][m][v] = U[b][m][v] / S[b][m]
__global__ __launch_bounds__(256) void slot_attn_finalize(
    const float* __restrict__ U, const float* __restrict__ S, float* __restrict__ out)
{
    int idx = blockIdx.x * 256 + threadIdx.x;  // 0..16383
    int b = idx >> 9;
    int m = (idx >> 6) & 7;
    out[idx] = U[idx] / S[b * NQ + m];
}

extern "C" void kernel_launch(void* const* d_in, const int* in_sizes, int n_in,
                              void* d_out, int out_size, void* d_ws, size_t ws_size,
                              hipStream_t stream) {
    const float* keys   = (const float*)d_in[0];
    const float* values = (const float*)d_in[1];
    const float* query  = (const float*)d_in[2];
    float* out = (float*)d_out;

    float* U = (float*)d_ws;                    // B*NQ*DV = 16384 floats
    float* S = U + BB * NQ * DV;                // B*NQ    = 256 floats

    hipMemsetAsync(d_ws, 0, (BB * NQ * DV + BB * NQ) * sizeof(float), stream);
    slot_attn_main<<<dim3(CHUNKS, BB), 256, 0, stream>>>(keys, values, query, U, S);
    slot_attn_finalize<<<dim3(64), 256, 0, stream>>>(U, S, out);
}